// Round 1
// baseline (197.342 us; speedup 1.0000x reference)
//
#include <hip/hip_runtime.h>

#define B_ 32
#define C_ 128
#define L_ 4096
#define P_ 100
#define Q_ 20
#define NBIN 21   // Q+1 buckets

// One block = one (b, 256-wide l-chunk). 256 threads, each thread owns one l.
// Thread keeps X[b, :, l] (128 floats) in VGPRs, loops over all P projections:
//   a = sum_c x[c]*W[p][c]   (W via wave-uniform index -> scalar loads)
//   k = clamp(floor((a - min_p) * (Q+1)/(max_p-min_p)), 0, 20)
//   LDS histogram atomicAdd
// Epilogue: per-(p,q) prefix sums of the block-local histogram, float atomicAdd
// into d_out (exact: multiples of 2^-12, totals <= 4096).
__global__ __launch_bounds__(256, 2)
void radon_hist_kernel(const float* __restrict__ X, const float* __restrict__ W,
                       const float* __restrict__ minv, const float* __restrict__ maxv,
                       float* __restrict__ out) {
    const int lchunk = blockIdx.x;          // 0..15
    const int b      = blockIdx.y;          // 0..31
    const int tid    = threadIdx.x;         // 0..255
    const int l      = lchunk * 256 + tid;

    __shared__ int hist[P_ * NBIN];
    for (int i = tid; i < P_ * NBIN; i += 256) hist[i] = 0;

    // Load this thread's X column into registers (coalesced across lanes per c).
    const float* Xb = X + ((size_t)b * C_) * L_ + l;
    float x[C_];
#pragma unroll
    for (int c = 0; c < C_; ++c) x[c] = Xb[(size_t)c * L_];

    __syncthreads();

    for (int p = 0; p < P_; ++p) {
        const float* Wp = W + p * C_;       // wave-uniform -> s_load path
        float a0 = 0.f, a1 = 0.f, a2 = 0.f, a3 = 0.f;
#pragma unroll
        for (int c = 0; c < C_; c += 4) {
            a0 += x[c + 0] * Wp[c + 0];
            a1 += x[c + 1] * Wp[c + 1];
            a2 += x[c + 2] * Wp[c + 2];
            a3 += x[c + 3] * Wp[c + 3];
        }
        const float a = (a0 + a1) + (a2 + a3);

        const float mn   = minv[p];
        const float invd = (float)NBIN / (maxv[p] - mn);
        const float t    = (a - mn) * invd;
        // k = #{q in 1..20 : thr_q <= a} = clamp(floor(t), 0, 20)
        int k = 0;
        if (t > 0.f) {
            int ki = (int)t;                // t >= 0 -> trunc == floor
            k = (ki > 20) ? 20 : ki;
        }
        atomicAdd(&hist[p * NBIN + k], 1);
    }
    __syncthreads();

    // cdf[b,p,qi] += (1/L) * sum_{k<=qi} hist[p][k]
    for (int i = tid; i < P_ * Q_; i += 256) {
        const int p  = i / Q_;
        const int qi = i - p * Q_;
        int s = 0;
        for (int k = 0; k <= qi; ++k) s += hist[p * NBIN + k];
        atomicAdd(&out[((size_t)b * P_ + p) * Q_ + qi], (float)s * (1.0f / (float)L_));
    }
}

extern "C" void kernel_launch(void* const* d_in, const int* in_sizes, int n_in,
                              void* d_out, int out_size, void* d_ws, size_t ws_size,
                              hipStream_t stream) {
    const float* X  = (const float*)d_in[0];
    const float* W  = (const float*)d_in[1];
    const float* mn = (const float*)d_in[2];
    const float* mx = (const float*)d_in[3];
    float* out = (float*)d_out;

    hipMemsetAsync(out, 0, (size_t)out_size * sizeof(float), stream);

    dim3 grid(L_ / 256, B_);
    radon_hist_kernel<<<grid, dim3(256), 0, stream>>>(X, W, mn, mx, out);
}

// Round 2
// 185.811 us; speedup vs baseline: 1.0621x; 1.0621x over previous
//
#include <hip/hip_runtime.h>

#define B_ 32
#define C_ 128
#define L_ 4096
#define P_ 100
#define PH 50      // p-half per block (p-split raises occupancy: 1024 blocks -> 4 waves/SIMD)
#define Q_ 20
#define NBIN 21    // Q+1 buckets

// Block = (b, 256-l chunk, p-half). Lane owns one l. Loop c outer:
//   - X[b][c][l] loaded ONCE (coalesced dword) -- accumulators (not inputs)
//     live in VGPRs, so the compiler cannot rematerialize them (R1 failure).
//   - W[p][c..c+3] is wave-uniform -> s_load_dwordx4 on the scalar pipe.
// Then bucket a into 21 uniform bins (thresholds are uniformly spaced),
// LDS histogram, prefix-sum, exact float atomicAdd into out.
__global__ __launch_bounds__(256, 4)
void radon_kernel(const float* __restrict__ X, const float* __restrict__ W,
                  const float* __restrict__ minv, const float* __restrict__ maxv,
                  float* __restrict__ out) {
    const int lchunk = blockIdx.x;   // 0..15
    const int b      = blockIdx.y;   // 0..31
    const int ph     = blockIdx.z;   // 0..1
    const int tid    = threadIdx.x;  // 0..255
    const int l      = lchunk * 256 + tid;
    const int p0     = ph * PH;

    __shared__ int hist[PH * NBIN];
    for (int i = tid; i < PH * NBIN; i += 256) hist[i] = 0;
    __syncthreads();

    float acc[PH];
#pragma unroll
    for (int p = 0; p < PH; ++p) acc[p] = 0.f;

    const float* Xp = X + ((size_t)b * C_) * L_ + l;
    const float* Wp = W + (size_t)p0 * C_;

    for (int c4 = 0; c4 < C_; c4 += 4) {
        const float x0 = Xp[(size_t)(c4 + 0) * L_];
        const float x1 = Xp[(size_t)(c4 + 1) * L_];
        const float x2 = Xp[(size_t)(c4 + 2) * L_];
        const float x3 = Xp[(size_t)(c4 + 3) * L_];
#pragma unroll
        for (int p = 0; p < PH; ++p) {
            const float4 w = *(const float4*)(Wp + p * C_ + c4);  // uniform -> s_load_dwordx4
            acc[p] = fmaf(x3, w.w, fmaf(x2, w.z, fmaf(x1, w.y, fmaf(x0, w.x, acc[p]))));
        }
    }

    // k = #{q in 1..20 : thr_q <= a} = clamp(floor((a-mn)*21/(mx-mn)), 0, 20)
#pragma unroll 4
    for (int p = 0; p < PH; ++p) {
        const float mn   = minv[p0 + p];
        const float invd = (float)NBIN / (maxv[p0 + p] - mn);
        const float t    = (acc[p] - mn) * invd;
        int k = 0;
        if (t > 0.f) { int ki = (int)t; k = (ki > 20) ? 20 : ki; }
        atomicAdd(&hist[p * NBIN + k], 1);
    }
    __syncthreads();

    // cdf[b, p0+p, qi] += (1/L) * prefix_sum(hist[p])[qi]
    // partial counts <= 256, scale 2^-12: every partial sum exact in fp32.
    for (int i = tid; i < PH * Q_; i += 256) {
        const int p  = i / Q_;
        const int qi = i - p * Q_;
        int s = 0;
        for (int k = 0; k <= qi; ++k) s += hist[p * NBIN + k];
        atomicAdd(&out[((size_t)b * P_ + p0 + p) * Q_ + qi],
                  (float)s * (1.0f / (float)L_));
    }
}

extern "C" void kernel_launch(void* const* d_in, const int* in_sizes, int n_in,
                              void* d_out, int out_size, void* d_ws, size_t ws_size,
                              hipStream_t stream) {
    const float* X  = (const float*)d_in[0];
    const float* W  = (const float*)d_in[1];
    const float* mn = (const float*)d_in[2];
    const float* mx = (const float*)d_in[3];
    float* out = (float*)d_out;

    hipMemsetAsync(out, 0, (size_t)out_size * sizeof(float), stream);

    dim3 grid(L_ / 256, B_, 2);
    radon_kernel<<<grid, dim3(256), 0, stream>>>(X, W, mn, mx, out);
}

// Round 3
// 172.401 us; speedup vs baseline: 1.1447x; 1.0778x over previous
//
#include <hip/hip_runtime.h>

#define B_ 32
#define C_ 128
#define L_ 4096
#define P_ 100
#define PG 25      // p per group: acc[25] = 25 VGPR, W float2 = 50 SGPR -- fits
#define NPG 2      // p-groups per block (2nd pass re-reads X from L2)
#define Q_ 20
#define NBIN 21    // Q+1 uniform buckets

// Block = (b, 256-l chunk, p-half). Lane owns one l. For each p-group of 25:
//   c-loop (NOT unrolled -- #pragma unroll 1 keeps s_load pressure bounded):
//     x0,x1 coalesced global dwords; 25 wave-uniform float2 W reads (s_load_dwordx2);
//     50 v_fma into acc[25] (register-resident: full unroll, constant indexing).
//   Bucket a into 21 uniform bins (thresholds uniformly spaced), LDS histogram,
//   prefix-sum, exact float atomicAdd into out (multiples of 2^-12, counts<=4096).
__global__ __launch_bounds__(256, 4)
void radon_kernel(const float* __restrict__ X, const float* __restrict__ W,
                  const float* __restrict__ minv, const float* __restrict__ maxv,
                  float* __restrict__ out) {
    const int lchunk = blockIdx.x;   // 0..15
    const int b      = blockIdx.y;   // 0..31
    const int zz     = blockIdx.z;   // 0..1
    const int tid    = threadIdx.x;  // 0..255
    const int l      = lchunk * 256 + tid;

    __shared__ int hist[PG * NBIN];

    const float* Xp = X + ((size_t)b * C_) * L_ + l;

    for (int g = 0; g < NPG; ++g) {
        const int p0 = (zz * NPG + g) * PG;

        for (int i = tid; i < PG * NBIN; i += 256) hist[i] = 0;
        __syncthreads();

        float acc[PG];
#pragma unroll
        for (int p = 0; p < PG; ++p) acc[p] = 0.f;

        const float* Wp = W + (size_t)p0 * C_;
#pragma unroll 1
        for (int c2 = 0; c2 < C_; c2 += 2) {
            const float x0 = Xp[(size_t)(c2 + 0) * L_];
            const float x1 = Xp[(size_t)(c2 + 1) * L_];
#pragma unroll
            for (int p = 0; p < PG; ++p) {
                const float2 w = *(const float2*)(Wp + p * C_ + c2);  // uniform -> s_load_dwordx2
                acc[p] = fmaf(x1, w.y, fmaf(x0, w.x, acc[p]));
            }
        }

        // k = #{q in 1..20 : thr_q <= a} = clamp(floor((a-mn)*21/(mx-mn)), 0, 20)
#pragma unroll
        for (int p = 0; p < PG; ++p) {
            const float mn   = minv[p0 + p];
            const float invd = (float)NBIN / (maxv[p0 + p] - mn);
            const float t    = (acc[p] - mn) * invd;
            int k = 0;
            if (t > 0.f) { int ki = (int)t; k = (ki > 20) ? 20 : ki; }
            atomicAdd(&hist[p * NBIN + k], 1);
        }
        __syncthreads();

        // cdf[b, p0+p, qi] += (1/L) * prefix_sum(hist[p])[qi]
        for (int i = tid; i < PG * Q_; i += 256) {
            const int p  = i / Q_;
            const int qi = i - p * Q_;
            int s = 0;
            for (int k = 0; k <= qi; ++k) s += hist[p * NBIN + k];
            atomicAdd(&out[((size_t)b * P_ + p0 + p) * Q_ + qi],
                      (float)s * (1.0f / (float)L_));
        }
        __syncthreads();   // hist re-zeroed next group
    }
}

extern "C" void kernel_launch(void* const* d_in, const int* in_sizes, int n_in,
                              void* d_out, int out_size, void* d_ws, size_t ws_size,
                              hipStream_t stream) {
    const float* X  = (const float*)d_in[0];
    const float* W  = (const float*)d_in[1];
    const float* mn = (const float*)d_in[2];
    const float* mx = (const float*)d_in[3];
    float* out = (float*)d_out;

    hipMemsetAsync(out, 0, (size_t)out_size * sizeof(float), stream);

    dim3 grid(L_ / 256, B_, 2);
    radon_kernel<<<grid, dim3(256), 0, stream>>>(X, W, mn, mx, out);
}

// Round 4
// 114.567 us; speedup vs baseline: 1.7225x; 1.5048x over previous
//
#include <hip/hip_runtime.h>
#include <hip/hip_bf16.h>

#define B_   32
#define C_   128
#define L_   4096
#define P_   100
#define PT   112          // P padded to 7 tiles of 16
#define NPT  7
#define Q_   20
#define NBIN 21
#define WROW 136          // W LDS row stride (bf16 elems): +8 pad -> 2-way bank alias (free)

typedef short  bf16x8 __attribute__((ext_vector_type(8)));
typedef float  f32x4  __attribute__((ext_vector_type(4)));

__device__ inline unsigned short f2bf(float f) {
    __hip_bfloat16 h = __float2bfloat16(f);   // round-to-nearest-even
    unsigned short u; __builtin_memcpy(&u, &h, 2);
    return u;
}

// Block = (b, 128-l chunk), 256 threads = 4 waves; wave owns 32 l (2 l-tiles of 16).
// GEMM via mfma_f32_16x16x32_bf16:  D[p][l] = sum_c W[p][c] * X[b][c][l]
//   A-frag (W, LDS):   A[m=lane&15][k=quad*8+j]        (m = p-row, k = c)
//   B-frag (X, VGPRs): B[k=quad*8+j][n=lane&15]        (n = l-col) -- X read ONCE
//   C/D:               col=lane&15, row=quad*4+reg     [m89-verified]
// Accumulators are bucketed directly (thresholds uniformly spaced -> bin index),
// LDS histogram + prefix-sum epilogue, exact fp32 atomicAdd (multiples of 2^-12).
__global__ __launch_bounds__(256, 4)
void radon_mfma_kernel(const float* __restrict__ X, const float* __restrict__ W,
                       const float* __restrict__ minv, const float* __restrict__ maxv,
                       float* __restrict__ out) {
    __shared__ unsigned short Wlds[PT * WROW];   // 30.5 KB
    __shared__ int   hist[P_ * NBIN];            // 8.4 KB
    __shared__ float mn_s[P_], invd_s[P_];       // 0.8 KB

    const int tid  = threadIdx.x;
    const int b    = blockIdx.y;
    const int lblk = blockIdx.x;       // 0..31
    const int wave = tid >> 6;
    const int lane = tid & 63;
    const int quad = lane >> 4;
    const int nn   = lane & 15;

    // ---- stage W -> LDS bf16 (rows >= P_ zeroed), float2 reads, packed writes
    for (int i = tid; i < PT * (C_ / 2); i += 256) {
        const int row = i / (C_ / 2);
        const int cp  = (i - row * (C_ / 2)) * 2;
        float2 w2 = make_float2(0.f, 0.f);
        if (row < P_) w2 = *(const float2*)(W + row * C_ + cp);
        const unsigned int pk = (unsigned int)f2bf(w2.x) | ((unsigned int)f2bf(w2.y) << 16);
        *(unsigned int*)(&Wlds[row * WROW + cp]) = pk;   // (row*136+cp)*2 is 4B-aligned
    }
    for (int i = tid; i < P_; i += 256) {
        const float mn = minv[i];
        mn_s[i]   = mn;
        invd_s[i] = (float)NBIN / (maxv[i] - mn);
    }
    for (int i = tid; i < P_ * NBIN; i += 256) hist[i] = 0;
    __syncthreads();

    // ---- B-frags: X[b][c][l] for this wave's 32 l, all 128 c, once, in VGPRs
    const int l0 = lblk * 128 + wave * 32;
    const float* Xb = X + (size_t)b * C_ * L_;
    bf16x8 bfrag[2][4];
#pragma unroll
    for (int lt = 0; lt < 2; ++lt) {
        const int l = l0 + lt * 16 + nn;
#pragma unroll
        for (int ks = 0; ks < 4; ++ks) {
            float xv[8];
#pragma unroll
            for (int j = 0; j < 8; ++j)
                xv[j] = Xb[(size_t)(ks * 32 + quad * 8 + j) * L_ + l];
            bf16x8 f;
#pragma unroll
            for (int j = 0; j < 8; ++j) f[j] = (short)f2bf(xv[j]);
            bfrag[lt][ks] = f;
        }
    }

    // ---- 7 p-tiles: LDS A-frags, 8 MFMAs, bucket accumulators into histogram
    for (int pt = 0; pt < NPT; ++pt) {
        const int p0 = pt * 16;
        bf16x8 afrag[4];
#pragma unroll
        for (int ks = 0; ks < 4; ++ks)   // 16B-aligned -> ds_read_b128, 2-way alias only
            afrag[ks] = *(const bf16x8*)(&Wlds[(p0 + nn) * WROW + ks * 32 + quad * 8]);

        f32x4 acc0 = {0.f, 0.f, 0.f, 0.f};
        f32x4 acc1 = {0.f, 0.f, 0.f, 0.f};
#pragma unroll
        for (int ks = 0; ks < 4; ++ks) {
            acc0 = __builtin_amdgcn_mfma_f32_16x16x32_bf16(afrag[ks], bfrag[0][ks], acc0, 0, 0, 0);
            acc1 = __builtin_amdgcn_mfma_f32_16x16x32_bf16(afrag[ks], bfrag[1][ks], acc1, 0, 0, 0);
        }

        // D row = quad*4 + r  ->  p = p0 + quad*4 + r   (skip pad rows p >= 100)
#pragma unroll
        for (int r = 0; r < 4; ++r) {
            const int p = p0 + quad * 4 + r;
            if (p < P_) {
                const float mn = mn_s[p], invd = invd_s[p];
                {
                    const float t = (acc0[r] - mn) * invd;
                    int k = 0;
                    if (t > 0.f) { const int ki = (int)t; k = (ki > 20) ? 20 : ki; }
                    atomicAdd(&hist[p * NBIN + k], 1);
                }
                {
                    const float t = (acc1[r] - mn) * invd;
                    int k = 0;
                    if (t > 0.f) { const int ki = (int)t; k = (ki > 20) ? 20 : ki; }
                    atomicAdd(&hist[p * NBIN + k], 1);
                }
            }
        }
    }
    __syncthreads();

    // ---- prefix-sum histogram -> exact fp32 atomic accumulation into out
    for (int i = tid; i < P_ * Q_; i += 256) {
        const int p  = i / Q_;
        const int qi = i - p * Q_;
        int s = 0;
        for (int k = 0; k <= qi; ++k) s += hist[p * NBIN + k];
        atomicAdd(&out[((size_t)b * P_ + p) * Q_ + qi], (float)s * (1.0f / (float)L_));
    }
}

extern "C" void kernel_launch(void* const* d_in, const int* in_sizes, int n_in,
                              void* d_out, int out_size, void* d_ws, size_t ws_size,
                              hipStream_t stream) {
    const float* X  = (const float*)d_in[0];
    const float* W  = (const float*)d_in[1];
    const float* mn = (const float*)d_in[2];
    const float* mx = (const float*)d_in[3];
    float* out = (float*)d_out;

    hipMemsetAsync(out, 0, (size_t)out_size * sizeof(float), stream);

    dim3 grid(L_ / 128, B_);
    radon_mfma_kernel<<<grid, dim3(256), 0, stream>>>(X, W, mn, mx, out);
}

// Round 5
// 110.656 us; speedup vs baseline: 1.7834x; 1.0353x over previous
//
#include <hip/hip_runtime.h>
#include <hip/hip_bf16.h>

#define B_   32
#define C_   128
#define L_   4096
#define P_   100
#define NPT  7            // p-tiles of 16 (P padded to 112)
#define Q_   20
#define NBIN 21
#define NCH  (NPT * 4)    // 28 A-frag chunks; chunk = pt*4 + ks
#define CHS  512          // shorts per chunk = 64 lanes * 8 bf16 (1 KB)

typedef short          bf16x8 __attribute__((ext_vector_type(8)));
typedef float          f32x4  __attribute__((ext_vector_type(4)));
typedef unsigned short u16x8  __attribute__((ext_vector_type(8)));

__device__ inline unsigned short f2bf(float f) {
    __hip_bfloat16 h = __float2bfloat16(f);   // RNE
    unsigned short u; __builtin_memcpy(&u, &h, 2);
    return u;
}

// ---- prep: W (fp32 [P][C]) -> bf16 A-fragment lane order in d_ws ----
// Wf[chunk][lane][j] with chunk=pt*4+ks: value = W[pt*16 + (lane&15)][ks*32 + (lane>>4)*8 + j]
// (rows p>=100 zero-padded). Main kernel then reads afrag = 16B at lane*16: canonical
// conflict-free ds_read_b128 after a trivial dwordx4 LDS copy.
__global__ void prep_w_kernel(const float* __restrict__ W, unsigned short* __restrict__ Wf) {
    const int t = blockIdx.x * 256 + threadIdx.x;     // 0 .. NCH*64-1
    if (t >= NCH * 64) return;
    const int chunk = t >> 6, lane = t & 63;
    const int pt = chunk >> 2, ks = chunk & 3;
    const int p  = pt * 16 + (lane & 15);
    const int c0 = ks * 32 + (lane >> 4) * 8;
    u16x8 v;
#pragma unroll
    for (int j = 0; j < 8; ++j)
        v[j] = (p < P_) ? f2bf(W[p * C_ + c0 + j]) : (unsigned short)0;
    *(u16x8*)(Wf + (size_t)t * 8) = v;                // 16B coalesced store
}

// ---- main: block = (b, 128-l chunk), 4 waves; wave owns 32 l (2 l-tiles) ----
// D[p][l] = sum_c W[p][c] * X[b][c][l] via mfma_f32_16x16x32_bf16.
//   B-frag (X): B[k=quad*8+j][n=lane&15], X read ONCE, loads issued FIRST so the
//               HBM drain overlaps W copy + hist init + cvt issue.
//   A-frag (W): pre-arranged bf16 from d_ws, 7 dwordx4 + 7 ds_write_b128 per thread.
//   C/D: col=lane&15, row=quad*4+reg [m89-verified]. Accumulators bucketed directly
//   into a 21-bin LDS histogram (thresholds uniformly spaced); prefix-sum epilogue,
//   exact fp32 atomicAdd (multiples of 2^-12, counts<=4096).
__global__ __launch_bounds__(256, 4)
void radon_mfma2_kernel(const float* __restrict__ X, const unsigned short* __restrict__ Wf,
                        const float* __restrict__ minv, const float* __restrict__ maxv,
                        float* __restrict__ out) {
    __shared__ unsigned short Wlds[NCH * CHS];   // 28.0 KB
    __shared__ int   hist[P_ * NBIN];            // 8.4 KB
    __shared__ float mn_s[P_], invd_s[P_];       // 0.8 KB

    const int tid  = threadIdx.x;
    const int b    = blockIdx.y;
    const int lblk = blockIdx.x;       // 0..31
    const int wave = tid >> 6;
    const int lane = tid & 63;
    const int quad = lane >> 4;
    const int nn   = lane & 15;

    // ---- 1. X loads first: the long pole (HBM), overlap everything behind it
    const int l0 = lblk * 128 + wave * 32;
    const float* Xb = X + (size_t)b * C_ * L_;
    float xv[2][4][8];
#pragma unroll
    for (int lt = 0; lt < 2; ++lt)
#pragma unroll
        for (int ks = 0; ks < 4; ++ks)
#pragma unroll
            for (int j = 0; j < 8; ++j)
                xv[lt][ks][j] = Xb[(size_t)(ks * 32 + quad * 8 + j) * L_ + l0 + lt * 16 + nn];

    // ---- 2. W fragment copy (L2-resident, no cvt) + small init work
    {
        const int4* src = (const int4*)Wf;
        int4* dst = (int4*)Wlds;
#pragma unroll
        for (int k = 0; k < NCH * 64 / 256; ++k)     // 7 iters
            dst[tid + k * 256] = src[tid + k * 256];
    }
    for (int i = tid; i < P_; i += 256) {
        const float mn = minv[i];
        mn_s[i]   = mn;
        invd_s[i] = (float)NBIN / (maxv[i] - mn);
    }
    for (int i = tid; i < P_ * NBIN; i += 256) hist[i] = 0;

    // ---- 3. packed cvt fp32 -> bf16 fragments
    bf16x8 bfrag[2][4];
#pragma unroll
    for (int lt = 0; lt < 2; ++lt)
#pragma unroll
        for (int ks = 0; ks < 4; ++ks) {
            unsigned int u[4];
#pragma unroll
            for (int jp = 0; jp < 4; ++jp) {
                __hip_bfloat162 h2 = __float22bfloat162_rn(
                    make_float2(xv[lt][ks][2 * jp], xv[lt][ks][2 * jp + 1]));
                __builtin_memcpy(&u[jp], &h2, 4);
            }
            __builtin_memcpy(&bfrag[lt][ks], u, 16);
        }
    __syncthreads();

    // ---- 4. 7 p-tiles: conflict-free A-frag reads, 8 MFMAs, bucket into histogram
    for (int pt = 0; pt < NPT; ++pt) {
        bf16x8 afrag[4];
#pragma unroll
        for (int ks = 0; ks < 4; ++ks)
            afrag[ks] = *(const bf16x8*)(&Wlds[((pt * 4 + ks) * 64 + lane) * 8]);

        f32x4 acc0 = {0.f, 0.f, 0.f, 0.f};
        f32x4 acc1 = {0.f, 0.f, 0.f, 0.f};
#pragma unroll
        for (int ks = 0; ks < 4; ++ks) {
            acc0 = __builtin_amdgcn_mfma_f32_16x16x32_bf16(afrag[ks], bfrag[0][ks], acc0, 0, 0, 0);
            acc1 = __builtin_amdgcn_mfma_f32_16x16x32_bf16(afrag[ks], bfrag[1][ks], acc1, 0, 0, 0);
        }

        // D row = quad*4 + r -> p = pt*16 + quad*4 + r (skip pad rows)
#pragma unroll
        for (int r = 0; r < 4; ++r) {
            const int p = pt * 16 + quad * 4 + r;
            if (p < P_) {
                const float mn = mn_s[p], invd = invd_s[p];
                {
                    const float t = (acc0[r] - mn) * invd;
                    int k = 0;
                    if (t > 0.f) { const int ki = (int)t; k = (ki > 20) ? 20 : ki; }
                    atomicAdd(&hist[p * NBIN + k], 1);
                }
                {
                    const float t = (acc1[r] - mn) * invd;
                    int k = 0;
                    if (t > 0.f) { const int ki = (int)t; k = (ki > 20) ? 20 : ki; }
                    atomicAdd(&hist[p * NBIN + k], 1);
                }
            }
        }
    }
    __syncthreads();

    // ---- 5. prefix-sum histogram -> exact fp32 atomic accumulation into out
    for (int i = tid; i < P_ * Q_; i += 256) {
        const int p  = i / Q_;
        const int qi = i - p * Q_;
        int s = 0;
        for (int k = 0; k <= qi; ++k) s += hist[p * NBIN + k];
        atomicAdd(&out[((size_t)b * P_ + p) * Q_ + qi], (float)s * (1.0f / (float)L_));
    }
}

extern "C" void kernel_launch(void* const* d_in, const int* in_sizes, int n_in,
                              void* d_out, int out_size, void* d_ws, size_t ws_size,
                              hipStream_t stream) {
    const float* X  = (const float*)d_in[0];
    const float* W  = (const float*)d_in[1];
    const float* mn = (const float*)d_in[2];
    const float* mx = (const float*)d_in[3];
    float* out = (float*)d_out;
    unsigned short* Wf = (unsigned short*)d_ws;   // needs NCH*64*16 = 28672 bytes

    prep_w_kernel<<<NCH * 64 / 256, 256, 0, stream>>>(W, Wf);
    hipMemsetAsync(out, 0, (size_t)out_size * sizeof(float), stream);

    dim3 grid(L_ / 128, B_);
    radon_mfma2_kernel<<<grid, dim3(256), 0, stream>>>(X, Wf, mn, mx, out);
}

// Round 6
// 108.528 us; speedup vs baseline: 1.8183x; 1.0196x over previous
//
#include <hip/hip_runtime.h>
#include <hip/hip_bf16.h>

#define B_   32
#define C_   128
#define L_   4096
#define P_   100
#define NPT  7            // p-tiles of 16 (P padded to 112)
#define Q_   20
#define NBIN 21
#define NCH  (NPT * 4)    // 28 A-frag chunks; chunk = pt*4 + ks
#define CHS  512          // shorts per chunk = 64 lanes * 8 bf16 (1 KB)

typedef short          bf16x8 __attribute__((ext_vector_type(8)));
typedef float          f32x4  __attribute__((ext_vector_type(4)));
typedef unsigned short u16x8  __attribute__((ext_vector_type(8)));

__device__ inline unsigned short f2bf(float f) {
    __hip_bfloat16 h = __float2bfloat16(f);   // RNE
    unsigned short u; __builtin_memcpy(&u, &h, 2);
    return u;
}

// ---- prep: W (fp32 [P][C]) -> bf16 A-fragment lane order in d_ws ----
// Wf[chunk][lane][j], chunk=pt*4+ks: value = W[pt*16 + (lane&15)][ks*32 + (lane>>4)*8 + j]
// (rows p>=100 zeroed). Main kernel reads afrag as 16B at lane*16 -> canonical
// conflict-free ds_read_b128 after a plain dwordx4 LDS copy.
__global__ void prep_w_kernel(const float* __restrict__ W, unsigned short* __restrict__ Wf) {
    const int t = blockIdx.x * 256 + threadIdx.x;     // 0 .. NCH*64-1
    if (t >= NCH * 64) return;
    const int chunk = t >> 6, lane = t & 63;
    const int pt = chunk >> 2, ks = chunk & 3;
    const int p  = pt * 16 + (lane & 15);
    const int c0 = ks * 32 + (lane >> 4) * 8;
    u16x8 v;
#pragma unroll
    for (int j = 0; j < 8; ++j)
        v[j] = (p < P_) ? f2bf(W[p * C_ + c0 + j]) : (unsigned short)0;
    *(u16x8*)(Wf + (size_t)t * 8) = v;                // 16B coalesced store
}

// ---- main: block = (b, 128-l chunk), 4 waves; wave owns 32 l (2 l-tiles) ----
// D[p][l] = sum_c W[p][c] * X[b][c][l] via mfma_f32_16x16x32_bf16.
// PHASE ORDER IS THE POINT (R5 post-mortem): vmcnt is in-order and __syncthreads
// drains vmcnt(0), so any barrier issued after the X loads serializes all waves
// into lockstep load-phase/compute-phase. Here: W->LDS + hist init + the ONLY
// pre-epilogue barrier happen BEFORE any X load; afterwards each wave streams
// loads -> cvt -> ds_read -> MFMA -> bucket with no barrier, so one wave's
// compute overlaps other waves' outstanding loads.
//   B-frag (X): B[k=quad*8+j][n=lane&15], X read ONCE from global.
//   A-frag (W): pre-arranged bf16, 7 dwordx4 + 7 ds_write_b128 per thread.
//   C/D: col=lane&15, row=quad*4+reg [m89-verified]. Accumulators bucketed
//   directly into a 21-bin LDS histogram (thresholds uniformly spaced);
//   prefix-sum epilogue, exact fp32 atomicAdd (multiples of 2^-12, counts<=4096).
__global__ __launch_bounds__(256, 4)
void radon_mfma3_kernel(const float* __restrict__ X, const unsigned short* __restrict__ Wf,
                        const float* __restrict__ minv, const float* __restrict__ maxv,
                        float* __restrict__ out) {
    __shared__ unsigned short Wlds[NCH * CHS];   // 28.0 KB
    __shared__ int   hist[P_ * NBIN];            // 8.4 KB
    __shared__ float mn_s[P_], invd_s[P_];       // 0.8 KB

    const int tid  = threadIdx.x;
    const int b    = blockIdx.y;
    const int lblk = blockIdx.x;       // 0..31
    const int wave = tid >> 6;
    const int lane = tid & 63;
    const int quad = lane >> 4;
    const int nn   = lane & 15;

    // ---- Phase A: W fragments -> LDS, thresholds, hist zero, barrier.
    {
        const int4* src = (const int4*)Wf;
        int4* dst = (int4*)Wlds;
#pragma unroll
        for (int k = 0; k < NCH * 64 / 256; ++k)     // 7 iters, L2-resident
            dst[tid + k * 256] = src[tid + k * 256];
    }
    for (int i = tid; i < P_; i += 256) {
        const float mn = minv[i];
        mn_s[i]   = mn;
        invd_s[i] = (float)NBIN / (maxv[i] - mn);
    }
    for (int i = tid; i < P_ * NBIN; i += 256) hist[i] = 0;
    __syncthreads();   // the ONLY barrier before the epilogue

    // ---- Phase B: X loads + packed cvt (compiler interleaves, fine-grained vmcnt)
    const int l0 = lblk * 128 + wave * 32;
    const float* Xb = X + (size_t)b * C_ * L_;
    float xv[2][4][8];
#pragma unroll
    for (int lt = 0; lt < 2; ++lt)
#pragma unroll
        for (int ks = 0; ks < 4; ++ks)
#pragma unroll
            for (int j = 0; j < 8; ++j)
                xv[lt][ks][j] = Xb[(size_t)(ks * 32 + quad * 8 + j) * L_ + l0 + lt * 16 + nn];

    bf16x8 bfrag[2][4];
#pragma unroll
    for (int lt = 0; lt < 2; ++lt)
#pragma unroll
        for (int ks = 0; ks < 4; ++ks) {
            unsigned int u[4];
#pragma unroll
            for (int jp = 0; jp < 4; ++jp) {
                __hip_bfloat162 h2 = __float22bfloat162_rn(
                    make_float2(xv[lt][ks][2 * jp], xv[lt][ks][2 * jp + 1]));
                __builtin_memcpy(&u[jp], &h2, 4);
            }
            __builtin_memcpy(&bfrag[lt][ks], u, 16);
        }

    // ---- Phase C: 7 p-tiles, no barrier: ds_read A-frags + 8 MFMAs + bucket
    for (int pt = 0; pt < NPT; ++pt) {
        bf16x8 afrag[4];
#pragma unroll
        for (int ks = 0; ks < 4; ++ks)
            afrag[ks] = *(const bf16x8*)(&Wlds[((pt * 4 + ks) * 64 + lane) * 8]);

        f32x4 acc0 = {0.f, 0.f, 0.f, 0.f};
        f32x4 acc1 = {0.f, 0.f, 0.f, 0.f};
#pragma unroll
        for (int ks = 0; ks < 4; ++ks) {
            acc0 = __builtin_amdgcn_mfma_f32_16x16x32_bf16(afrag[ks], bfrag[0][ks], acc0, 0, 0, 0);
            acc1 = __builtin_amdgcn_mfma_f32_16x16x32_bf16(afrag[ks], bfrag[1][ks], acc1, 0, 0, 0);
        }

        // D row = quad*4 + r -> p = pt*16 + quad*4 + r (skip pad rows)
#pragma unroll
        for (int r = 0; r < 4; ++r) {
            const int p = pt * 16 + quad * 4 + r;
            if (p < P_) {
                const float mn = mn_s[p], invd = invd_s[p];
                {
                    const float t = (acc0[r] - mn) * invd;
                    int k = 0;
                    if (t > 0.f) { const int ki = (int)t; k = (ki > 20) ? 20 : ki; }
                    atomicAdd(&hist[p * NBIN + k], 1);
                }
                {
                    const float t = (acc1[r] - mn) * invd;
                    int k = 0;
                    if (t > 0.f) { const int ki = (int)t; k = (ki > 20) ? 20 : ki; }
                    atomicAdd(&hist[p * NBIN + k], 1);
                }
            }
        }
    }
    __syncthreads();

    // ---- Phase D: prefix-sum histogram -> exact fp32 atomic accumulation
    for (int i = tid; i < P_ * Q_; i += 256) {
        const int p  = i / Q_;
        const int qi = i - p * Q_;
        int s = 0;
        for (int k = 0; k <= qi; ++k) s += hist[p * NBIN + k];
        atomicAdd(&out[((size_t)b * P_ + p) * Q_ + qi], (float)s * (1.0f / (float)L_));
    }
}

extern "C" void kernel_launch(void* const* d_in, const int* in_sizes, int n_in,
                              void* d_out, int out_size, void* d_ws, size_t ws_size,
                              hipStream_t stream) {
    const float* X  = (const float*)d_in[0];
    const float* W  = (const float*)d_in[1];
    const float* mn = (const float*)d_in[2];
    const float* mx = (const float*)d_in[3];
    float* out = (float*)d_out;
    unsigned short* Wf = (unsigned short*)d_ws;   // needs NCH*64*16 = 28672 bytes

    hipMemsetAsync(out, 0, (size_t)out_size * sizeof(float), stream);
    prep_w_kernel<<<NCH * 64 / 256, 256, 0, stream>>>(W, Wf);

    dim3 grid(L_ / 128, B_);
    radon_mfma3_kernel<<<grid, dim3(256), 0, stream>>>(X, Wf, mn, mx, out);
}